// Round 19
// baseline (79.529 us; speedup 1.0000x reference)
//
#include <hip/hip_runtime.h>

typedef unsigned short u16;
typedef unsigned int u32;
typedef unsigned long long u64;
typedef __attribute__((ext_vector_type(8))) short bf16x8;
typedef __attribute__((ext_vector_type(4))) float f32x4;
typedef __attribute__((ext_vector_type(16))) float f32x16;
typedef __attribute__((ext_vector_type(4))) u32 u32x4;
typedef __attribute__((ext_vector_type(4))) int i32x4;
typedef __attribute__((ext_vector_type(4))) u16 u16x4t;

// async global->LDS, 16B per lane; LDS dest is wave-uniform base + lane*16
#define GLOAD16(gp, lp)                                                        \
  __builtin_amdgcn_global_load_lds(                                            \
      (__attribute__((address_space(1))) void*)(gp),                           \
      (__attribute__((address_space(3))) void*)(lp), 16, 0, 0)

#if __has_builtin(__builtin_amdgcn_exp2f)
#define EXP2(x) __builtin_amdgcn_exp2f(x)
#else
#define EXP2(x) __expf(0.6931471805599453f * (x))
#endif

#define Z16                                                                    \
  { 0.f, 0.f, 0.f, 0.f, 0.f, 0.f, 0.f, 0.f, 0.f, 0.f, 0.f, 0.f, 0.f, 0.f,     \
    0.f, 0.f }

__device__ __forceinline__ u16 f2bf(float f) {
  u32 u = __builtin_bit_cast(u32, f);
  u += 0x7FFFu + ((u >> 16) & 1u);  // RNE
  return (u16)(u >> 16);
}

__device__ __forceinline__ float bf2f(short s) {
  return __builtin_bit_cast(float, (u32)(u16)s << 16);
}

__device__ __forceinline__ u32 cvtpk(float lo, float hi) {
  u32 r;
  asm("v_cvt_pk_bf16_f32 %0, %1, %2" : "=v"(r) : "v"(lo), "v"(hi));
  return r;
}

// exchanges a's lanes 32-63 with b's lanes 0-31
__device__ __forceinline__ void plswap(u32& a, u32& b) {
  asm volatile("v_permlane32_swap_b32 %0, %1" : "+v"(a), "+v"(b));
}

__device__ __forceinline__ f32x4 MFMA(bf16x8 a, bf16x8 b, f32x4 c) {
  return __builtin_amdgcn_mfma_f32_16x16x32_bf16(a, b, c, 0, 0, 0);
}
__device__ __forceinline__ f32x16 MFMA32(bf16x8 a, bf16x8 b, f32x16 c) {
  return __builtin_amdgcn_mfma_f32_32x32x16_bf16(a, b, c, 0, 0, 0);
}

// convert 8 fp32 (2x f32x4) -> one 16B bf16 chunk
__device__ __forceinline__ u32x4 cvt8(f32x4 a, f32x4 b) {
  u32x4 o;
  o[0] = cvtpk(a[0], a[1]);
  o[1] = cvtpk(a[2], a[3]);
  o[2] = cvtpk(b[0], b[1]);
  o[3] = cvtpk(b[2], b[3]);
  return o;
}

// ---------------------------------------------------------------- kproj
// z<3: X(4096x128 fp32) @ W(1024x128 fp32)^T, bf16 MFMA (r10-proven).
// z=0: Q (scaled 1/(sqrt(128)ln2), (b,h,s,d)); z=1: K; z=2: V^T (b,h,d,s).
// z==3 (512 blocks): bias prefill + Wu fp32->bf16 + ballot-free mask pack.
__global__ __launch_bounds__(256) void kproj(
    const float* __restrict__ Xq, const float* __restrict__ Xk,
    const float* __restrict__ Xv, const float* __restrict__ Wqf,
    const float* __restrict__ Wkf, const float* __restrict__ Wvf,
    const int* __restrict__ mask, const float* __restrict__ bu,
    const float* __restrict__ Wuf, u16* __restrict__ Qh, u16* __restrict__ Kh,
    u16* __restrict__ Vt, u64* __restrict__ pm64, u16* __restrict__ Wub16,
    float* __restrict__ outp) {
  const int z = blockIdx.z;
  const int mt = blockIdx.x, nt = blockIdx.y;
  const int tid = threadIdx.x;
  if (z == 3) {
    const int fid = mt + nt * 32;     // 0..511
    const int idx = fid * 256 + tid;  // 0..131071
    f32x4 bv = *(const f32x4*)(bu + ((idx * 4) & 127));
    *((f32x4*)outp + idx) = bv;  // bias prefill
    if (idx < 32768) {           // Wu fp32 -> bf16
      f32x4 wv4 = *(const f32x4*)(Wuf + (size_t)idx * 4);
      u16x4t o;
      o[0] = f2bf(wv4[0]); o[1] = f2bf(wv4[1]);
      o[2] = f2bf(wv4[2]); o[3] = f2bf(wv4[3]);
      *(u16x4t*)(Wub16 + (size_t)idx * 4) = o;
    }
#pragma unroll
    for (int j = 0; j < 2; j++) {  // mask pack: 2 u32 words per thread
      const u32 W = fid * 512 + j * 256 + tid;
      const u32 half = W & 1, q = (W >> 1) & 2047, t5 = (W >> 12) & 31,
                b = W >> 17;
      const int* src =
          mask + ((size_t)b * 2048 + q) * 2048 + t5 * 64 + half * 32;
      i32x4 v[8];
#pragma unroll
      for (int k = 0; k < 8; k++) v[k] = *(const i32x4*)(src + k * 4);
      u32 wbits = 0;
#pragma unroll
      for (int k = 0; k < 8; k++) {
        if (v[k][0]) wbits |= 1u << (k * 4 + 0);
        if (v[k][1]) wbits |= 1u << (k * 4 + 1);
        if (v[k][2]) wbits |= 1u << (k * 4 + 2);
        if (v[k][3]) wbits |= 1u << (k * 4 + 3);
      }
      ((u32*)pm64)[W] = wbits;
    }
    return;
  }
  __shared__ alignas(128) u16 ldsA[128 * 128];  // 32 KB
  __shared__ alignas(128) u16 ldsB[64 * 128];   // 16 KB
  const float* X = z == 0 ? Xq : (z == 1 ? Xk : Xv);
  const float* W = z == 0 ? Wqf : (z == 1 ? Wkf : Wvf);
  const int w = tid >> 6, lane = tid & 63;
  const int lo = lane & 15, hi = lane >> 4;

#pragma unroll
  for (int i = 0; i < 8; i++) {
    int cid = i * 256 + tid;
    int r = cid >> 4, c = cid & 15;
    const float* src = X + (size_t)(mt * 128 + r) * 128 + c * 8;
    f32x4 a = *(const f32x4*)src;
    f32x4 b = *(const f32x4*)(src + 4);
    *(u32x4*)(ldsA + r * 128 + (c ^ (r & 7)) * 8) = cvt8(a, b);
  }
#pragma unroll
  for (int i = 0; i < 4; i++) {
    int cid = i * 256 + tid;
    int r = cid >> 4, c = cid & 15;
    const float* src = W + (size_t)(nt * 64 + r) * 128 + c * 8;
    f32x4 a = *(const f32x4*)src;
    f32x4 b = *(const f32x4*)(src + 4);
    *(u32x4*)(ldsB + r * 128 + (c ^ (r & 7)) * 8) = cvt8(a, b);
  }
  __syncthreads();

  const int wm = (w >> 1) * 64, wn = (w & 1) * 32;
  f32x4 zero = {0.f, 0.f, 0.f, 0.f};
  f32x4 acc[4][2];
#pragma unroll
  for (int a = 0; a < 4; a++)
#pragma unroll
    for (int b2 = 0; b2 < 2; b2++) acc[a][b2] = zero;

#pragma unroll
  for (int t = 0; t < 4; t++) {
    bf16x8 af[4], bfr[2];
#pragma unroll
    for (int fm = 0; fm < 4; fm++) {
      int r = wm + fm * 16 + lo;
      int ch = (t * 4 + hi) ^ (r & 7);
      af[fm] = *(const bf16x8*)(ldsA + r * 128 + ch * 8);
    }
#pragma unroll
    for (int fn = 0; fn < 2; fn++) {
      int r = wn + fn * 16 + lo;
      int ch = (t * 4 + hi) ^ (r & 7);
      bfr[fn] = *(const bf16x8*)(ldsB + r * 128 + ch * 8);
    }
#pragma unroll
    for (int fm = 0; fm < 4; fm++)
#pragma unroll
      for (int fn = 0; fn < 2; fn++)
        acc[fm][fn] = MFMA(af[fm], bfr[fn], acc[fm][fn]);
  }

  if (z < 2) {
    u16* dst = z == 0 ? Qh : Kh;
    const float scale = z == 0 ? 0.12753103392461437f : 1.0f;
#pragma unroll
    for (int fm = 0; fm < 4; fm++)
#pragma unroll
      for (int fn = 0; fn < 2; fn++) {
        int n = nt * 64 + wn + fn * 16 + lo;
        int h = n >> 7, d = n & 127;
#pragma unroll
        for (int j = 0; j < 4; j++) {
          int m = mt * 128 + wm + fm * 16 + hi * 4 + j;
          int b = m >> 11, s = m & 2047;
          dst[(((size_t)(b * 8 + h) * 2048) + s) * 128 + d] =
              f2bf(acc[fm][fn][j] * scale);
        }
      }
  } else {
#pragma unroll
    for (int fm = 0; fm < 4; fm++)
#pragma unroll
      for (int fn = 0; fn < 2; fn++) {
        int n = nt * 64 + wn + fn * 16 + lo;
        int h = n >> 7, d = n & 127;
        int m0 = mt * 128 + wm + fm * 16 + hi * 4;
        int b = m0 >> 11, s0 = m0 & 2047;
        u16x4t pk4;
#pragma unroll
        for (int j = 0; j < 4; j++) pk4[j] = f2bf(acc[fm][fn][j]);
        *(u16x4t*)(Vt + ((size_t)(b * 8 + h) * 128 + d) * 2048 + s0) = pk4;
      }
  }
}

// ---------------------------------------------------------------- kattn
// r14-proven core with SINGLE-BARRIER tile sync: per tile
// { vmcnt(0) -> barrier -> mask load -> STAGE(t+1) -> compute(t) }.
// The pre-barrier drain proves RAW (each wave's stage(t) landed before it
// crossed) AND the barrier proves WAR (all compute(t-1) reads done before
// anyone overwrites buf[(t+1)&1]) -- so B_mid is gone: 16 barriers/block
// instead of 32. Double buffer, compute code identical. vmcnt(0) sits a
// full compute-phase (~3000 cyc) after stage issue vs ~900 cyc latency.
// Fixed-shift softmax (CSH=24), l via ones-column in matrix pipe.
// __launch_bounds__(256,2): VGPR ~104 + ~80 acc; min-waves>=3 spills
// (r6/r7/r15: VGPR=64, 300MB scratch). nsplit=2, grid (16,2,16).
__global__ __launch_bounds__(256, 2) void kattn(
    const u16* __restrict__ Qh, const u16* __restrict__ Kh,
    const u16* __restrict__ Vt, const u64* __restrict__ pm64,
    u16* __restrict__ OP, float2* __restrict__ ML, int ntiles) {
  __shared__ alignas(128) u16 ldsK[2][64 * 128];  // 2 x 16 KB, row = k_local
  __shared__ alignas(128) u16 ldsV[2][128 * 64];  // 2 x 16 KB, row = d
  const int bh = blockIdx.x;       // bh fastest -> XCD-friendly
  const int half = blockIdx.y;     // 0..nsplit-1
  const int qblk = blockIdx.z;     // 0..15
  const int b = bh >> 3, h = bh & 7;
  const int ktbase = half * ntiles;
  u16* outO = OP + (size_t)half * 4194304;
  const float CSH = 24.0f;  // fixed softmax shift (exp2 units)

  const int tid = threadIdx.x, w = tid >> 6, lane = tid & 63;
  const int lo5 = lane & 31, h5 = lane >> 5;
  const int q0w = qblk * 128 + w * 32;
  const int q = q0w + lo5;
  const u16* Qb = Qh + (size_t)bh * 262144;
  const u16* Kb = Kh + (size_t)bh * 262144;
  const u16* Vb = Vt + (size_t)bh * 262144;
  const u64* pmb = pm64 + ((size_t)b << 16);  // [32 tiles][2048 q]

  // per-lane staging offsets (loop-invariant)
  int kgo[4], vgo[4], slo[4];
#pragma unroll
  for (int i = 0; i < 4; i++) {
    int off = (w * 4 + i) * 1024 + lane * 16;
    slo[i] = off;
    { int r = off >> 8, c = (off >> 4) & 15, gs = c ^ (r & 7);
      kgo[i] = r * 128 + gs * 8; }
    { int d = off >> 7, c = (off >> 4) & 7, gs = c ^ (d & 7);
      vgo[i] = d * 2048 + gs * 8; }
  }
  // per-lane fragment-read offsets (bytes, loop-invariant)
  int kro[8], vro[4];
#pragma unroll
  for (int ds = 0; ds < 8; ds++)
    kro[ds] = lo5 * 256 + (((ds * 2 + h5) ^ (lo5 & 7)) * 16);
#pragma unroll
  for (int g2 = 0; g2 < 4; g2++)
    vro[g2] = lo5 * 128 + (((g2 * 2 + h5) ^ (lo5 & 7)) * 16);

  // ones-column B-frag: B[k][d]=1 only for d-col 0 -> C[.][col0] = row sums
  bf16x8 vones;
  {
    u32 onesw = (lo5 == 0) ? 0x3F803F80u : 0u;  // bf16 1.0 pair
    u32x4 t = {onesw, onesw, onesw, onesw};
    vones = __builtin_bit_cast(bf16x8, t);
  }

#define STAGE(kt, bb)                                                          \
  do {                                                                         \
    const int k0_ = (kt) * 64;                                                 \
    _Pragma("unroll") for (int i = 0; i < 4; i++)                              \
        GLOAD16(Kb + (size_t)k0_ * 128 + kgo[i],                               \
                (char*)ldsK + (bb) * 16384 + slo[i]);                          \
    _Pragma("unroll") for (int i = 0; i < 4; i++)                              \
        GLOAD16(Vb + k0_ + vgo[i], (char*)ldsV + (bb) * 16384 + slo[i]);       \
  } while (0)

  // Q B-frags: B[d][q], lane holds col q = lo5, rows d = ds*16 + h5*8 + j
  bf16x8 qb[8];
#pragma unroll
  for (int ds = 0; ds < 8; ds++)
    qb[ds] = *(const bf16x8*)(Qb + (size_t)q * 128 + ds * 16 + h5 * 8);

  asm volatile("" ::: "memory");
  STAGE(ktbase, 0);
  asm volatile("" ::: "memory");

  f32x16 o0 = Z16, o1 = Z16, o2 = Z16, o3 = Z16, o4 = Z16;

  for (int t = 0; t < ntiles; ++t) {
    const int bb = t & 1;
    // single-barrier sync: drain my stage(t) fully, THEN barrier. After the
    // barrier every wave's stage(t) has landed (RAW) and every wave has
    // finished compute(t-1)'s reads of buf[bb^1] (WAR for STAGE(t+1)).
    asm volatile("s_waitcnt vmcnt(0)" ::: "memory");
    __builtin_amdgcn_sched_barrier(0);
    __builtin_amdgcn_s_barrier();
    // mask load first (its compiler wait drains only itself, leaving the 8
    // stage ops in flight), then next-tile prefetch.
    u64 mw = pmb[((size_t)(ktbase + t) << 11) + q];
    if (t + 1 < ntiles) STAGE(ktbase + t + 1, bb ^ 1);
    const char* Kt = (const char*)ldsK + bb * 16384;
    const char* Vl = (const char*)ldsV + bb * 16384;

    // ---- S' = K Q^T: C col = q = lo5, row k = (r&3)+8*(r>>2)+4*h5 (+32*kk)
    f32x16 s0v = Z16, s1v = Z16;
    __builtin_amdgcn_s_setprio(1);
#pragma unroll
    for (int ds = 0; ds < 8; ds++) {
      bf16x8 ka0 = *(const bf16x8*)(Kt + kro[ds]);
      bf16x8 ka1 = *(const bf16x8*)(Kt + kro[ds] + 8192);
      s0v = MFMA32(ka0, qb[ds], s0v);
      s1v = MFMA32(ka1, qb[ds], s1v);
    }
    __builtin_amdgcn_s_setprio(0);

    // ---- P = exp2(S - CSH), zeroed by mask bits
    const u32 mw0 = (u32)mw, mw1 = (u32)(mw >> 32);
#pragma unroll
    for (int r = 0; r < 16; r++) {
      const int rowr = (r & 3) + 8 * (r >> 2) + 4 * h5;
      float p0 = EXP2(s0v[r] - CSH);
      float p1 = EXP2(s1v[r] - CSH);
      p0 = ((mw0 >> rowr) & 1u) ? p0 : 0.0f;
      p1 = ((mw1 >> rowr) & 1u) ? p1 : 0.0f;
      s0v[r] = p0;
      s1v[r] = p1;
    }

    // ---- P -> bf16 A-frags: cvt_pk pairs + permlane32_swap (T12)
    bf16x8 pa[4];
#pragma unroll
    for (int kk = 0; kk < 2; kk++)
#pragma unroll
      for (int sl = 0; sl < 2; sl++) {
        const int rb = sl * 8;
        u32 W0, W1, W2, W3;
        if (kk == 0) {
          W0 = cvtpk(s0v[rb + 0], s0v[rb + 1]);
          W1 = cvtpk(s0v[rb + 2], s0v[rb + 3]);
          W2 = cvtpk(s0v[rb + 4], s0v[rb + 5]);
          W3 = cvtpk(s0v[rb + 6], s0v[rb + 7]);
        } else {
          W0 = cvtpk(s1v[rb + 0], s1v[rb + 1]);
          W1 = cvtpk(s1v[rb + 2], s1v[rb + 3]);
          W2 = cvtpk(s1v[rb + 4], s1v[rb + 5]);
          W3 = cvtpk(s1v[rb + 6], s1v[rb + 7]);
        }
        plswap(W0, W2);
        plswap(W1, W3);
        u32x4 tt = {W0, W1, W2, W3};
        pa[kk * 2 + sl] = __builtin_bit_cast(bf16x8, tt);
      }

    // ---- PV: O[q][d] += P x V; l[q] += P x ones (matrix pipe, o4 col 0)
    __builtin_amdgcn_s_setprio(1);
#pragma unroll
    for (int gsl = 0; gsl < 4; gsl++) {
      bf16x8 vb0 = *(const bf16x8*)(Vl + vro[gsl] + 0 * 4096);
      bf16x8 vb1 = *(const bf16x8*)(Vl + vro[gsl] + 1 * 4096);
      bf16x8 vb2 = *(const bf16x8*)(Vl + vro[gsl] + 2 * 4096);
      bf16x8 vb3 = *(const bf16x8*)(Vl + vro[gsl] + 3 * 4096);
      o0 = MFMA32(pa[gsl], vb0, o0);
      o1 = MFMA32(pa[gsl], vb1, o1);
      o2 = MFMA32(pa[gsl], vb2, o2);
      o3 = MFMA32(pa[gsl], vb3, o3);
      o4 = MFMA32(pa[gsl], vones, o4);
    }
    __builtin_amdgcn_s_setprio(0);
  }
#undef STAGE

  // epilogue: l[rowr(r,h5)] lives in lane h5*32's o4[r] (col 0). Pull per-r.
  float linv4[16];
#pragma unroll
  for (int r = 0; r < 16; r++) {
    float lr_ = __shfl(o4[r], h5 * 32);
    linv4[r] = lr_ > 0.f ? 1.0f / lr_ : 0.f;
  }
#pragma unroll
  for (int r = 0; r < 16; r++) {
    const int rowr = (r & 3) + 8 * (r >> 2) + 4 * h5;
    const float fr = linv4[r];
    const size_t base =
        ((size_t)(b * 2048 + q0w + rowr)) * 1024 + h * 128 + lo5;
    outO[base + 0] = f2bf(o0[r] * fr);
    outO[base + 32] = f2bf(o1[r] * fr);
    outO[base + 64] = f2bf(o2[r] * fr);
    outO[base + 96] = f2bf(o3[r] * fr);
  }
  // ML: holder lanes (lo5==0) store (CSH, l) for their 16 rows
  if (lo5 == 0) {
#pragma unroll
    for (int r = 0; r < 16; r++) {
      const int rowr = (r & 3) + 8 * (r >> 2) + 4 * h5;
      ML[((size_t)half << 15) + ((size_t)bh << 11) + q0w + rowr] =
          make_float2(CSH, o4[r]);
    }
  }
}

// ---------------------------------------------------------------- koutf
// out += merge(OP halves; ML) @ Wu^T + (bias prefilled), split-K x4 (2 heads
// per block), fp32 HW atomics. SINGLE-BARRIER, 32-row M-tiles: grid (128,4)
// = 512 blocks, LDS 80 KB -> 2 blocks/CU; waves split 2 row-strips x 2
// col-halves. W re-reads double but Wu-bf16 (256 KB) is L2-resident.
__global__ __launch_bounds__(256) void koutf(
    const u16* __restrict__ OP, const float2* __restrict__ ML,
    const u16* __restrict__ Wub16, float* __restrict__ out, int nsplit) {
  __shared__ alignas(128) u16 ldsA[2][32 * 128];   // 16 KB
  __shared__ alignas(128) u16 ldsW[2][128 * 128];  // 64 KB
  const int mt = blockIdx.x;  // 0..127 (32-row tiles)
  const int kc = blockIdx.y;  // 0..3
  const int tid = threadIdx.x, w = tid >> 6, lane = tid & 63;
  const int lo = lane & 15, hi = lane >> 4;
  const int wr = w & 1, wc = w >> 1;  // row strip / col half

  // ---- async W staging, both chunks (8 GLOAD16 per wave per chunk)
#pragma unroll
  for (int ks = 0; ks < 2; ks++) {
    const int k0 = (kc * 2 + ks) * 128;
#pragma unroll
    for (int i = 0; i < 8; i++) {
      int off = (w * 8 + i) * 1024 + lane * 16;
      int r = off >> 8, c = (off >> 4) & 15, g = c ^ (r & 7);
      GLOAD16(Wub16 + (size_t)r * 1024 + k0 + g * 8, (char*)ldsW[ks] + off);
    }
  }
  // ---- A staging with fused flash-combine, both chunks (reg -> LDS)
#pragma unroll
  for (int ks = 0; ks < 2; ks++) {
    const int h = kc * 2 + ks;
    const int k0 = h * 128;
#pragma unroll
    for (int i = 0; i < 2; i++) {
      int cid = i * 256 + tid;
      int r = cid >> 4, c = cid & 15;
      int m = mt * 32 + r, b = m >> 11, q = m & 2047;
      size_t off = (size_t)m * 1024 + k0 + c * 8;
      bf16x8 x = *(const bf16x8*)(OP + off);
      u32x4 ow;
      if (nsplit == 2) {
        bf16x8 y = *(const bf16x8*)(OP + 4194304 + off);
        size_t mli = (((size_t)(b << 3) + h) << 11) + q;
        float2 A = ML[mli];
        float2 Bv = ML[32768 + mli];
        float mm = fmaxf(A.x, Bv.x);
        float w1 = A.y * EXP2(A.x - mm);
        float w2 = Bv.y * EXP2(Bv.x - mm);
        float inv = 1.0f / (w1 + w2);
        w1 *= inv;
        w2 *= inv;
        float f[8];
#pragma unroll
        for (int j = 0; j < 8; j++) f[j] = w1 * bf2f(x[j]) + w2 * bf2f(y[j]);
        ow[0] = cvtpk(f[0], f[1]);
        ow[1] = cvtpk(f[2], f[3]);
        ow[2] = cvtpk(f[4], f[5]);
        ow[3] = cvtpk(f[6], f[7]);
      } else {
        ow = __builtin_bit_cast(u32x4, x);
      }
      *(u32x4*)(ldsA[ks] + r * 128 + (c ^ (r & 7)) * 8) = ow;
    }
  }
  __syncthreads();  // drains vmcnt (GLOAD16) + lgkmcnt (ds_write) once

  f32x4 zero = {0.f, 0.f, 0.f, 0.f};
  f32x4 acc[4];
#pragma unroll
  for (int fn = 0; fn < 4; fn++) acc[fn] = zero;
  __builtin_amdgcn_s_setprio(1);
#pragma unroll
  for (int ks = 0; ks < 2; ks++) {
#pragma unroll
    for (int t = 0; t < 4; t++) {
      int ra = wr * 16 + lo, cha = (t * 4 + hi) ^ (ra & 7);
      bf16x8 af = *(const bf16x8*)(ldsA[ks] + ra * 128 + cha * 8);
#pragma unroll
      for (int fn = 0; fn < 4; fn++) {
        int rb = wc * 64 + fn * 16 + lo, chb = (t * 4 + hi) ^ (rb & 7);
        bf16x8 bf_ = *(const bf16x8*)(ldsW[ks] + rb * 128 + chb * 8);
        acc[fn] = MFMA(af, bf_, acc[fn]);
      }
    }
  }
  __builtin_amdgcn_s_setprio(0);

#pragma unroll
  for (int fn = 0; fn < 4; fn++) {
    int n = wc * 64 + fn * 16 + lo;
#pragma unroll
    for (int j = 0; j < 4; j++) {
      int m = mt * 32 + wr * 16 + hi * 4 + j;
      unsafeAtomicAdd(&out[(size_t)m * 128 + n], acc[fn][j]);
    }
  }
}

// ---------------------------------------------------------------- launch
extern "C" void kernel_launch(void* const* d_in, const int* in_sizes, int n_in,
                              void* d_out, int out_size, void* d_ws,
                              size_t ws_size, hipStream_t stream) {
  const float* values = (const float*)d_in[0];
  const float* keys = (const float*)d_in[1];
  const float* query = (const float*)d_in[2];
  const int* mask = (const int*)d_in[3];
  const float* Wv = (const float*)d_in[4];
  const float* Wk = (const float*)d_in[5];
  const float* Wq = (const float*)d_in[6];
  const float* Wu = (const float*)d_in[7];
  const float* bu = (const float*)d_in[8];

  char* ws = (char*)d_ws;
  u16* QH = (u16*)(ws + 0);           // (b,h,s,d) scaled    8 MB
  u16* KH = (u16*)(ws + 8388608);     // (b,h,s,d)           8 MB
  u16* VT = (u16*)(ws + 16777216);    // (b,h,d,s)           8 MB
  u64* PM64 = (u64*)(ws + 25165824);  // mask pm64[b][t][q]  1 MB
  float2* MLb = (float2*)(ws + 26214400);  // (m,l) x 2     512 KB
  u16* WUB16 = (u16*)(ws + 26738688);      // Wu bf16       256 KB
  u16* OP = (u16*)(ws + 27262976);    // O partials, 8 MB each

  const size_t base = 27262976;
  int nsplit = (ws_size >= base + 2ull * 8388608) ? 2 : 1;
  int ntiles = 32 / nsplit;

  float* out = (float*)d_out;
  kproj<<<dim3(32, 16, 4), 256, 0, stream>>>(query, keys, values, Wq, Wk, Wv,
                                             mask, bu, Wu, QH, KH, VT, PM64,
                                             WUB16, out);
  kattn<<<dim3(16, nsplit, 16), 256, 0, stream>>>(QH, KH, VT, PM64, OP, MLb,
                                                  ntiles);
  koutf<<<dim3(128, 4), 256, 0, stream>>>(OP, MLb, WUB16, out, nsplit);
}

// Round 20
// 78.098 us; speedup vs baseline: 1.0183x; 1.0183x over previous
//
#include <hip/hip_runtime.h>

typedef unsigned short u16;
typedef unsigned int u32;
typedef unsigned long long u64;
typedef __attribute__((ext_vector_type(8))) short bf16x8;
typedef __attribute__((ext_vector_type(4))) float f32x4;
typedef __attribute__((ext_vector_type(16))) float f32x16;
typedef __attribute__((ext_vector_type(4))) u32 u32x4;
typedef __attribute__((ext_vector_type(4))) int i32x4;
typedef __attribute__((ext_vector_type(4))) u16 u16x4t;

// async global->LDS, 16B per lane; LDS dest is wave-uniform base + lane*16
#define GLOAD16(gp, lp)                                                        \
  __builtin_amdgcn_global_load_lds(                                            \
      (__attribute__((address_space(1))) void*)(gp),                           \
      (__attribute__((address_space(3))) void*)(lp), 16, 0, 0)

#if __has_builtin(__builtin_amdgcn_exp2f)
#define EXP2(x) __builtin_amdgcn_exp2f(x)
#else
#define EXP2(x) __expf(0.6931471805599453f * (x))
#endif

#define Z16                                                                    \
  { 0.f, 0.f, 0.f, 0.f, 0.f, 0.f, 0.f, 0.f, 0.f, 0.f, 0.f, 0.f, 0.f, 0.f,     \
    0.f, 0.f }
// accumulator pre-init with the fixed softmax shift: QK^T MFMA chain then
// yields S' - 24 directly (C-in is added for free by the matrix pipe),
// eliminating 32 v_sub per tile per wave.
#define MSH16                                                                  \
  { -24.f, -24.f, -24.f, -24.f, -24.f, -24.f, -24.f, -24.f, -24.f, -24.f,     \
    -24.f, -24.f, -24.f, -24.f, -24.f, -24.f }

__device__ __forceinline__ u16 f2bf(float f) {
  u32 u = __builtin_bit_cast(u32, f);
  u += 0x7FFFu + ((u >> 16) & 1u);  // RNE
  return (u16)(u >> 16);
}

__device__ __forceinline__ float bf2f(short s) {
  return __builtin_bit_cast(float, (u32)(u16)s << 16);
}

__device__ __forceinline__ u32 cvtpk(float lo, float hi) {
  u32 r;
  asm("v_cvt_pk_bf16_f32 %0, %1, %2" : "=v"(r) : "v"(lo), "v"(hi));
  return r;
}

// exchanges a's lanes 32-63 with b's lanes 0-31
__device__ __forceinline__ void plswap(u32& a, u32& b) {
  asm volatile("v_permlane32_swap_b32 %0, %1" : "+v"(a), "+v"(b));
}

__device__ __forceinline__ f32x4 MFMA(bf16x8 a, bf16x8 b, f32x4 c) {
  return __builtin_amdgcn_mfma_f32_16x16x32_bf16(a, b, c, 0, 0, 0);
}
__device__ __forceinline__ f32x16 MFMA32(bf16x8 a, bf16x8 b, f32x16 c) {
  return __builtin_amdgcn_mfma_f32_32x32x16_bf16(a, b, c, 0, 0, 0);
}

// convert 8 fp32 (2x f32x4) -> one 16B bf16 chunk
__device__ __forceinline__ u32x4 cvt8(f32x4 a, f32x4 b) {
  u32x4 o;
  o[0] = cvtpk(a[0], a[1]);
  o[1] = cvtpk(a[2], a[3]);
  o[2] = cvtpk(b[0], b[1]);
  o[3] = cvtpk(b[2], b[3]);
  return o;
}

// ---------------------------------------------------------------- kproj
// z<3: X(4096x128 fp32) @ W(1024x128 fp32)^T, bf16 MFMA (r10-proven).
// z=0: Q (scaled 1/(sqrt(128)ln2), (b,h,s,d)); z=1: K; z=2: V^T (b,h,d,s).
// z==3 (512 blocks): bias prefill + Wu fp32->bf16 + ballot-free mask pack.
__global__ __launch_bounds__(256) void kproj(
    const float* __restrict__ Xq, const float* __restrict__ Xk,
    const float* __restrict__ Xv, const float* __restrict__ Wqf,
    const float* __restrict__ Wkf, const float* __restrict__ Wvf,
    const int* __restrict__ mask, const float* __restrict__ bu,
    const float* __restrict__ Wuf, u16* __restrict__ Qh, u16* __restrict__ Kh,
    u16* __restrict__ Vt, u64* __restrict__ pm64, u16* __restrict__ Wub16,
    float* __restrict__ outp) {
  const int z = blockIdx.z;
  const int mt = blockIdx.x, nt = blockIdx.y;
  const int tid = threadIdx.x;
  if (z == 3) {
    const int fid = mt + nt * 32;     // 0..511
    const int idx = fid * 256 + tid;  // 0..131071
    f32x4 bv = *(const f32x4*)(bu + ((idx * 4) & 127));
    *((f32x4*)outp + idx) = bv;  // bias prefill
    if (idx < 32768) {           // Wu fp32 -> bf16
      f32x4 wv4 = *(const f32x4*)(Wuf + (size_t)idx * 4);
      u16x4t o;
      o[0] = f2bf(wv4[0]); o[1] = f2bf(wv4[1]);
      o[2] = f2bf(wv4[2]); o[3] = f2bf(wv4[3]);
      *(u16x4t*)(Wub16 + (size_t)idx * 4) = o;
    }
#pragma unroll
    for (int j = 0; j < 2; j++) {  // mask pack: 2 u32 words per thread
      const u32 W = fid * 512 + j * 256 + tid;
      const u32 half = W & 1, q = (W >> 1) & 2047, t5 = (W >> 12) & 31,
                b = W >> 17;
      const int* src =
          mask + ((size_t)b * 2048 + q) * 2048 + t5 * 64 + half * 32;
      i32x4 v[8];
#pragma unroll
      for (int k = 0; k < 8; k++) v[k] = *(const i32x4*)(src + k * 4);
      u32 wbits = 0;
#pragma unroll
      for (int k = 0; k < 8; k++) {
        if (v[k][0]) wbits |= 1u << (k * 4 + 0);
        if (v[k][1]) wbits |= 1u << (k * 4 + 1);
        if (v[k][2]) wbits |= 1u << (k * 4 + 2);
        if (v[k][3]) wbits |= 1u << (k * 4 + 3);
      }
      ((u32*)pm64)[W] = wbits;
    }
    return;
  }
  __shared__ alignas(128) u16 ldsA[128 * 128];  // 32 KB
  __shared__ alignas(128) u16 ldsB[64 * 128];   // 16 KB
  const float* X = z == 0 ? Xq : (z == 1 ? Xk : Xv);
  const float* W = z == 0 ? Wqf : (z == 1 ? Wkf : Wvf);
  const int w = tid >> 6, lane = tid & 63;
  const int lo = lane & 15, hi = lane >> 4;

#pragma unroll
  for (int i = 0; i < 8; i++) {
    int cid = i * 256 + tid;
    int r = cid >> 4, c = cid & 15;
    const float* src = X + (size_t)(mt * 128 + r) * 128 + c * 8;
    f32x4 a = *(const f32x4*)src;
    f32x4 b = *(const f32x4*)(src + 4);
    *(u32x4*)(ldsA + r * 128 + (c ^ (r & 7)) * 8) = cvt8(a, b);
  }
#pragma unroll
  for (int i = 0; i < 4; i++) {
    int cid = i * 256 + tid;
    int r = cid >> 4, c = cid & 15;
    const float* src = W + (size_t)(nt * 64 + r) * 128 + c * 8;
    f32x4 a = *(const f32x4*)src;
    f32x4 b = *(const f32x4*)(src + 4);
    *(u32x4*)(ldsB + r * 128 + (c ^ (r & 7)) * 8) = cvt8(a, b);
  }
  __syncthreads();

  const int wm = (w >> 1) * 64, wn = (w & 1) * 32;
  f32x4 zero = {0.f, 0.f, 0.f, 0.f};
  f32x4 acc[4][2];
#pragma unroll
  for (int a = 0; a < 4; a++)
#pragma unroll
    for (int b2 = 0; b2 < 2; b2++) acc[a][b2] = zero;

#pragma unroll
  for (int t = 0; t < 4; t++) {
    bf16x8 af[4], bfr[2];
#pragma unroll
    for (int fm = 0; fm < 4; fm++) {
      int r = wm + fm * 16 + lo;
      int ch = (t * 4 + hi) ^ (r & 7);
      af[fm] = *(const bf16x8*)(ldsA + r * 128 + ch * 8);
    }
#pragma unroll
    for (int fn = 0; fn < 2; fn++) {
      int r = wn + fn * 16 + lo;
      int ch = (t * 4 + hi) ^ (r & 7);
      bfr[fn] = *(const bf16x8*)(ldsB + r * 128 + ch * 8);
    }
#pragma unroll
    for (int fm = 0; fm < 4; fm++)
#pragma unroll
      for (int fn = 0; fn < 2; fn++)
        acc[fm][fn] = MFMA(af[fm], bfr[fn], acc[fm][fn]);
  }

  if (z < 2) {
    u16* dst = z == 0 ? Qh : Kh;
    const float scale = z == 0 ? 0.12753103392461437f : 1.0f;
#pragma unroll
    for (int fm = 0; fm < 4; fm++)
#pragma unroll
      for (int fn = 0; fn < 2; fn++) {
        int n = nt * 64 + wn + fn * 16 + lo;
        int h = n >> 7, d = n & 127;
#pragma unroll
        for (int j = 0; j < 4; j++) {
          int m = mt * 128 + wm + fm * 16 + hi * 4 + j;
          int b = m >> 11, s = m & 2047;
          dst[(((size_t)(b * 8 + h) * 2048) + s) * 128 + d] =
              f2bf(acc[fm][fn][j] * scale);
        }
      }
  } else {
#pragma unroll
    for (int fm = 0; fm < 4; fm++)
#pragma unroll
      for (int fn = 0; fn < 2; fn++) {
        int n = nt * 64 + wn + fn * 16 + lo;
        int h = n >> 7, d = n & 127;
        int m0 = mt * 128 + wm + fm * 16 + hi * 4;
        int b = m0 >> 11, s0 = m0 & 2047;
        u16x4t pk4;
#pragma unroll
        for (int j = 0; j < 4; j++) pk4[j] = f2bf(acc[fm][fn][j]);
        *(u16x4t*)(Vt + ((size_t)(b * 8 + h) * 128 + d) * 2048 + s0) = pk4;
      }
  }
}

// ---------------------------------------------------------------- kattn
// r19 single-barrier core + shift folded into MFMA C-init: s0v/s1v start
// at -24, so QK^T produces S'-24 directly and the 32 v_sub/tile vanish.
// Fixed-shift softmax (no max/rescale), l via ones-column in matrix pipe.
// __launch_bounds__(256,2): VGPR ~104 + ~80 acc; min-waves>=3 spills
// (r6/r7/r15: VGPR=64, 300MB scratch). nsplit=2, grid (16,2,16).
__global__ __launch_bounds__(256, 2) void kattn(
    const u16* __restrict__ Qh, const u16* __restrict__ Kh,
    const u16* __restrict__ Vt, const u64* __restrict__ pm64,
    u16* __restrict__ OP, float2* __restrict__ ML, int ntiles) {
  __shared__ alignas(128) u16 ldsK[2][64 * 128];  // 2 x 16 KB, row = k_local
  __shared__ alignas(128) u16 ldsV[2][128 * 64];  // 2 x 16 KB, row = d
  const int bh = blockIdx.x;       // bh fastest -> XCD-friendly
  const int half = blockIdx.y;     // 0..nsplit-1
  const int qblk = blockIdx.z;     // 0..15
  const int b = bh >> 3, h = bh & 7;
  const int ktbase = half * ntiles;
  u16* outO = OP + (size_t)half * 4194304;
  const float CSH = 24.0f;  // fixed softmax shift (exp2 units)

  const int tid = threadIdx.x, w = tid >> 6, lane = tid & 63;
  const int lo5 = lane & 31, h5 = lane >> 5;
  const int q0w = qblk * 128 + w * 32;
  const int q = q0w + lo5;
  const u16* Qb = Qh + (size_t)bh * 262144;
  const u16* Kb = Kh + (size_t)bh * 262144;
  const u16* Vb = Vt + (size_t)bh * 262144;
  const u64* pmb = pm64 + ((size_t)b << 16);  // [32 tiles][2048 q]

  // per-lane staging offsets (loop-invariant)
  int kgo[4], vgo[4], slo[4];
#pragma unroll
  for (int i = 0; i < 4; i++) {
    int off = (w * 4 + i) * 1024 + lane * 16;
    slo[i] = off;
    { int r = off >> 8, c = (off >> 4) & 15, gs = c ^ (r & 7);
      kgo[i] = r * 128 + gs * 8; }
    { int d = off >> 7, c = (off >> 4) & 7, gs = c ^ (d & 7);
      vgo[i] = d * 2048 + gs * 8; }
  }
  // per-lane fragment-read offsets (bytes, loop-invariant)
  int kro[8], vro[4];
#pragma unroll
  for (int ds = 0; ds < 8; ds++)
    kro[ds] = lo5 * 256 + (((ds * 2 + h5) ^ (lo5 & 7)) * 16);
#pragma unroll
  for (int g2 = 0; g2 < 4; g2++)
    vro[g2] = lo5 * 128 + (((g2 * 2 + h5) ^ (lo5 & 7)) * 16);

  // ones-column B-frag: B[k][d]=1 only for d-col 0 -> C[.][col0] = row sums
  bf16x8 vones;
  {
    u32 onesw = (lo5 == 0) ? 0x3F803F80u : 0u;  // bf16 1.0 pair
    u32x4 t = {onesw, onesw, onesw, onesw};
    vones = __builtin_bit_cast(bf16x8, t);
  }

#define STAGE(kt, bb)                                                          \
  do {                                                                         \
    const int k0_ = (kt) * 64;                                                 \
    _Pragma("unroll") for (int i = 0; i < 4; i++)                              \
        GLOAD16(Kb + (size_t)k0_ * 128 + kgo[i],                               \
                (char*)ldsK + (bb) * 16384 + slo[i]);                          \
    _Pragma("unroll") for (int i = 0; i < 4; i++)                              \
        GLOAD16(Vb + k0_ + vgo[i], (char*)ldsV + (bb) * 16384 + slo[i]);       \
  } while (0)

  // Q B-frags: B[d][q], lane holds col q = lo5, rows d = ds*16 + h5*8 + j
  bf16x8 qb[8];
#pragma unroll
  for (int ds = 0; ds < 8; ds++)
    qb[ds] = *(const bf16x8*)(Qb + (size_t)q * 128 + ds * 16 + h5 * 8);

  asm volatile("" ::: "memory");
  STAGE(ktbase, 0);
  asm volatile("" ::: "memory");

  f32x16 o0 = Z16, o1 = Z16, o2 = Z16, o3 = Z16, o4 = Z16;

  for (int t = 0; t < ntiles; ++t) {
    const int bb = t & 1;
    // single-barrier sync: drain my stage(t) fully, THEN barrier. After the
    // barrier every wave's stage(t) has landed (RAW) and every wave has
    // finished compute(t-1)'s reads of buf[bb^1] (WAR for STAGE(t+1)).
    asm volatile("s_waitcnt vmcnt(0)" ::: "memory");
    __builtin_amdgcn_sched_barrier(0);
    __builtin_amdgcn_s_barrier();
    // mask load first (its compiler wait drains only itself), then prefetch.
    u64 mw = pmb[((size_t)(ktbase + t) << 11) + q];
    if (t + 1 < ntiles) STAGE(ktbase + t + 1, bb ^ 1);
    const char* Kt = (const char*)ldsK + bb * 16384;
    const char* Vl = (const char*)ldsV + bb * 16384;

    // ---- S' - CSH = K Q^T + (-CSH): C col = q = lo5,
    // row k = (r&3)+8*(r>>2)+4*h5 (+32*kk). Shift rides in the C operand.
    f32x16 s0v = MSH16, s1v = MSH16;
    __builtin_amdgcn_s_setprio(1);
#pragma unroll
    for (int ds = 0; ds < 8; ds++) {
      bf16x8 ka0 = *(const bf16x8*)(Kt + kro[ds]);
      bf16x8 ka1 = *(const bf16x8*)(Kt + kro[ds] + 8192);
      s0v = MFMA32(ka0, qb[ds], s0v);
      s1v = MFMA32(ka1, qb[ds], s1v);
    }
    __builtin_amdgcn_s_setprio(0);

    // ---- P = exp2(S - CSH) directly, zeroed by mask bits
    const u32 mw0 = (u32)mw, mw1 = (u32)(mw >> 32);
#pragma unroll
    for (int r = 0; r < 16; r++) {
      const int rowr = (r & 3) + 8 * (r >> 2) + 4 * h5;
      float p0 = EXP2(s0v[r]);
      float p1 = EXP2(s1v[r]);
      p0 = ((mw0 >> rowr) & 1u) ? p0 : 0.0f;
      p1 = ((mw1 >> rowr) & 1u) ? p1 : 0.0f;
      s0v[r] = p0;
      s1v[r] = p1;
    }

    // ---- P -> bf16 A-frags: cvt_pk pairs + permlane32_swap (T12)
    bf16x8 pa[4];
#pragma unroll
    for (int kk = 0; kk < 2; kk++)
#pragma unroll
      for (int sl = 0; sl < 2; sl++) {
        const int rb = sl * 8;
        u32 W0, W1, W2, W3;
        if (kk == 0) {
          W0 = cvtpk(s0v[rb + 0], s0v[rb + 1]);
          W1 = cvtpk(s0v[rb + 2], s0v[rb + 3]);
          W2 = cvtpk(s0v[rb + 4], s0v[rb + 5]);
          W3 = cvtpk(s0v[rb + 6], s0v[rb + 7]);
        } else {
          W0 = cvtpk(s1v[rb + 0], s1v[rb + 1]);
          W1 = cvtpk(s1v[rb + 2], s1v[rb + 3]);
          W2 = cvtpk(s1v[rb + 4], s1v[rb + 5]);
          W3 = cvtpk(s1v[rb + 6], s1v[rb + 7]);
        }
        plswap(W0, W2);
        plswap(W1, W3);
        u32x4 tt = {W0, W1, W2, W3};
        pa[kk * 2 + sl] = __builtin_bit_cast(bf16x8, tt);
      }

    // ---- PV: O[q][d] += P x V; l[q] += P x ones (matrix pipe, o4 col 0)
    __builtin_amdgcn_s_setprio(1);
#pragma unroll
    for (int gsl = 0; gsl < 4; gsl++) {
      bf16x8 vb0 = *(const bf16x8*)(Vl + vro[gsl] + 0 * 4096);
      bf16x8 vb1 = *(const bf16x8*)(Vl + vro[gsl] + 1 * 4096);
      bf16x8 vb2 = *(const bf16x8*)(Vl + vro[gsl] + 2 * 4096);
      bf16x8 vb3 = *(const bf16x8*)(Vl + vro[gsl] + 3 * 4096);
      o0 = MFMA32(pa[gsl], vb0, o0);
      o1 = MFMA32(pa[gsl], vb1, o1);
      o2 = MFMA32(pa[gsl], vb2, o2);
      o3 = MFMA32(pa[gsl], vb3, o3);
      o4 = MFMA32(pa[gsl], vones, o4);
    }
    __builtin_amdgcn_s_setprio(0);
  }
#undef STAGE

  // epilogue: l[rowr(r,h5)] lives in lane h5*32's o4[r] (col 0). Pull per-r.
  float linv4[16];
#pragma unroll
  for (int r = 0; r < 16; r++) {
    float lr_ = __shfl(o4[r], h5 * 32);
    linv4[r] = lr_ > 0.f ? 1.0f / lr_ : 0.f;
  }
#pragma unroll
  for (int r = 0; r < 16; r++) {
    const int rowr = (r & 3) + 8 * (r >> 2) + 4 * h5;
    const float fr = linv4[r];
    const size_t base =
        ((size_t)(b * 2048 + q0w + rowr)) * 1024 + h * 128 + lo5;
    outO[base + 0] = f2bf(o0[r] * fr);
    outO[base + 32] = f2bf(o1[r] * fr);
    outO[base + 64] = f2bf(o2[r] * fr);
    outO[base + 96] = f2bf(o3[r] * fr);
  }
  // ML: holder lanes (lo5==0) store (CSH, l) for their 16 rows
  if (lo5 == 0) {
#pragma unroll
    for (int r = 0; r < 16; r++) {
      const int rowr = (r & 3) + 8 * (r >> 2) + 4 * h5;
      ML[((size_t)half << 15) + ((size_t)bh << 11) + q0w + rowr] =
          make_float2(CSH, o4[r]);
    }
  }
}

// ---------------------------------------------------------------- koutf
// out += merge(OP halves; ML) @ Wu^T + (bias prefilled), split-K x4 (2 heads
// per block), fp32 HW atomics. SINGLE-BARRIER, 32-row M-tiles: grid (128,4)
// = 512 blocks, LDS 80 KB -> 2 blocks/CU; waves split 2 row-strips x 2
// col-halves. W re-reads double but Wu-bf16 (256 KB) is L2-resident.
__global__ __launch_bounds__(256) void koutf(
    const u16* __restrict__ OP, const float2* __restrict__ ML,
    const u16* __restrict__ Wub16, float* __restrict__ out, int nsplit) {
  __shared__ alignas(128) u16 ldsA[2][32 * 128];   // 16 KB
  __shared__ alignas(128) u16 ldsW[2][128 * 128];  // 64 KB
  const int mt = blockIdx.x;  // 0..127 (32-row tiles)
  const int kc = blockIdx.y;  // 0..3
  const int tid = threadIdx.x, w = tid >> 6, lane = tid & 63;
  const int lo = lane & 15, hi = lane >> 4;
  const int wr = w & 1, wc = w >> 1;  // row strip / col half

  // ---- async W staging, both chunks (8 GLOAD16 per wave per chunk)
#pragma unroll
  for (int ks = 0; ks < 2; ks++) {
    const int k0 = (kc * 2 + ks) * 128;
#pragma unroll
    for (int i = 0; i < 8; i++) {
      int off = (w * 8 + i) * 1024 + lane * 16;
      int r = off >> 8, c = (off >> 4) & 15, g = c ^ (r & 7);
      GLOAD16(Wub16 + (size_t)r * 1024 + k0 + g * 8, (char*)ldsW[ks] + off);
    }
  }
  // ---- A staging with fused flash-combine, both chunks (reg -> LDS)
#pragma unroll
  for (int ks = 0; ks < 2; ks++) {
    const int h = kc * 2 + ks;
    const int k0 = h * 128;
#pragma unroll
    for (int i = 0; i < 2; i++) {
      int cid = i * 256 + tid;
      int r = cid >> 4, c = cid & 15;
      int m = mt * 32 + r, b = m >> 11, q = m & 2047;
      size_t off = (size_t)m * 1024 + k0 + c * 8;
      bf16x8 x = *(const bf16x8*)(OP + off);
      u32x4 ow;
      if (nsplit == 2) {
        bf16x8 y = *(const bf16x8*)(OP + 4194304 + off);
        size_t mli = (((size_t)(b << 3) + h) << 11) + q;
        float2 A = ML[mli];
        float2 Bv = ML[32768 + mli];
        float mm = fmaxf(A.x, Bv.x);
        float w1 = A.y * EXP2(A.x - mm);
        float w2 = Bv.y * EXP2(Bv.x - mm);
        float inv = 1.0f / (w1 + w2);
        w1 *= inv;
        w2 *= inv;
        float f[8];
#pragma unroll
        for (int j = 0; j < 8; j++) f[j] = w1 * bf2f(x[j]) + w2 * bf2f(y[j]);
        ow[0] = cvtpk(f[0], f[1]);
        ow[1] = cvtpk(f[2], f[3]);
        ow[2] = cvtpk(f[4], f[5]);
        ow[3] = cvtpk(f[6], f[7]);
      } else {
        ow = __builtin_bit_cast(u32x4, x);
      }
      *(u32x4*)(ldsA[ks] + r * 128 + (c ^ (r & 7)) * 8) = ow;
    }
  }
  __syncthreads();  // drains vmcnt (GLOAD16) + lgkmcnt (ds_write) once

  f32x4 zero = {0.f, 0.f, 0.f, 0.f};
  f32x4 acc[4];
#pragma unroll
  for (int fn = 0; fn < 4; fn++) acc[fn] = zero;
  __builtin_amdgcn_s_setprio(1);
#pragma unroll
  for (int ks = 0; ks < 2; ks++) {
#pragma unroll
    for (int t = 0; t < 4; t++) {
      int ra = wr * 16 + lo, cha = (t * 4 + hi) ^ (ra & 7);
      bf16x8 af = *(const bf16x8*)(ldsA[ks] + ra * 128 + cha * 8);
#pragma unroll
      for (int fn = 0; fn < 4; fn++) {
        int rb = wc * 64 + fn * 16 + lo, chb = (t * 4 + hi) ^ (rb & 7);
        bf16x8 bf_ = *(const bf16x8*)(ldsW[ks] + rb * 128 + chb * 8);
        acc[fn] = MFMA(af, bf_, acc[fn]);
      }
    }
  }
  __builtin_amdgcn_s_setprio(0);

#pragma unroll
  for (int fn = 0; fn < 4; fn++) {
    int n = wc * 64 + fn * 16 + lo;
#pragma unroll
    for (int j = 0; j < 4; j++) {
      int m = mt * 32 + wr * 16 + hi * 4 + j;
      unsafeAtomicAdd(&out[(size_t)m * 128 + n], acc[fn][j]);
    }
  }
}

// ---------------------------------------------------------------- launch
extern "C" void kernel_launch(void* const* d_in, const int* in_sizes, int n_in,
                              void* d_out, int out_size, void* d_ws,
                              size_t ws_size, hipStream_t stream) {
  const float* values = (const float*)d_in[0];
  const float* keys = (const float*)d_in[1];
  const float* query = (const float*)d_in[2];
  const int* mask = (const int*)d_in[3];
  const float* Wv = (const float*)d_in[4];
  const float* Wk = (const float*)d_in[5];
  const float* Wq = (const float*)d_in[6];
  const float* Wu = (const float*)d_in[7];
  const float* bu = (const float*)d_in[8];

  char* ws = (char*)d_ws;
  u16* QH = (u16*)(ws + 0);           // (b,h,s,d) scaled    8 MB
  u16* KH = (u16*)(ws + 8388608);     // (b,h,s,d)           8 MB
  u16* VT = (u16*)(ws + 16777216);    // (b,h,d,s)           8 MB
  u64* PM64 = (u64*)(ws + 25165824);  // mask pm64[b][t][q]  1 MB
  float2* MLb = (float2*)(ws + 26214400);  // (m,l) x 2     512 KB
  u16* WUB16 = (u16*)(ws + 26738688);      // Wu bf16       256 KB
  u16* OP = (u16*)(ws + 27262976);    // O partials, 8 MB each

  const size_t base = 27262976;
  int nsplit = (ws_size >= base + 2ull * 8388608) ? 2 : 1;
  int ntiles = 32 / nsplit;

  float* out = (float*)d_out;
  kproj<<<dim3(32, 16, 4), 256, 0, stream>>>(query, keys, values, Wq, Wk, Wv,
                                             mask, bu, Wu, QH, KH, VT, PM64,
                                             WUB16, out);
  kattn<<<dim3(16, nsplit, 16), 256, 0, stream>>>(QH, KH, VT, PM64, OP, MLb,
                                                  ntiles);
  koutf<<<dim3(128, 4), 256, 0, stream>>>(OP, MLb, WUB16, out, nsplit);
}